// Round 1
// baseline (396.056 us; speedup 1.0000x reference)
//
#include <hip/hip_runtime.h>
#include <stdint.h>

// B=4, T=2048, C=1024, H=16, d_k=64. fp32 in/out, bf16 MFMA compute.

typedef __bf16 bf16_t;
typedef __bf16 bf16x4 __attribute__((ext_vector_type(4)));
typedef __bf16 bf16x8 __attribute__((ext_vector_type(8)));
typedef float f32x4 __attribute__((ext_vector_type(4)));

#define LOG2E 1.44269504088896340736f

__device__ __forceinline__ void gl_lds16(const void* g, void* l) {
  __builtin_amdgcn_global_load_lds(
      (const __attribute__((address_space(1))) unsigned int*)g,
      (__attribute__((address_space(3))) unsigned int*)l, 16, 0, 0);
}

__device__ __forceinline__ f32x4 mfma16(bf16x8 a, bf16x8 b, f32x4 c) {
  return __builtin_amdgcn_mfma_f32_16x16x32_bf16(a, b, c, 0, 0, 0);
}

// ---------------- fp32 -> bf16 vectorized convert ----------------
__global__ __launch_bounds__(256) void k_cvt_bf16(const float* __restrict__ in,
                                                  bf16_t* __restrict__ out, int n4) {
  int i = blockIdx.x * 256 + threadIdx.x;
  int step = gridDim.x * 256;
  for (; i < n4; i += step) {
    f32x4 v = reinterpret_cast<const f32x4*>(in)[i];
    bf16x4 o;
    o[0] = (bf16_t)v[0]; o[1] = (bf16_t)v[1];
    o[2] = (bf16_t)v[2]; o[3] = (bf16_t)v[3];
    reinterpret_cast<bf16x4*>(out)[i] = o;
  }
}

// ------------- fp32 [R][Cc] -> bf16 [Cc][R] tiled transpose -------------
__global__ __launch_bounds__(256) void k_transpose_cvt(const float* __restrict__ in,
                                                       bf16_t* __restrict__ out,
                                                       int R, int Cc) {
  __shared__ float tile[64][65];
  const int tid = threadIdx.x;
  const int c0 = blockIdx.x * 64, r0 = blockIdx.y * 64;
  const int rr = tid >> 4, cc = (tid & 15) * 4;
#pragma unroll
  for (int i = 0; i < 4; i++) {
    f32x4 v = *reinterpret_cast<const f32x4*>(&in[(size_t)(r0 + rr + i * 16) * Cc + c0 + cc]);
    tile[rr + i * 16][cc + 0] = v[0];
    tile[rr + i * 16][cc + 1] = v[1];
    tile[rr + i * 16][cc + 2] = v[2];
    tile[rr + i * 16][cc + 3] = v[3];
  }
  __syncthreads();
  const int cr = tid >> 2, kb = (tid & 3) * 16;
#pragma unroll
  for (int j4 = 0; j4 < 4; j4++) {
    bf16x4 o;
#pragma unroll
    for (int jj = 0; jj < 4; jj++) o[jj] = (bf16_t)tile[kb + j4 * 4 + jj][cr];
    *reinterpret_cast<bf16x4*>(&out[(size_t)(c0 + cr) * R + r0 + kb + j4 * 4]) = o;
  }
}

// ---------------- bf16 GEMM: C[M][N] = A[M][K] * Bt[N][K]^T ----------------
// MODE 1: QKV epilogue -> Q,K cols [0,2048) to qk[M][2048]; V cols to vT[b,h,d,t] bf16
// MODE 2: fp32 C[M][N] epilogue
template <int MODE>
__global__ __launch_bounds__(256) void k_gemm(const bf16_t* __restrict__ A,
                                              const bf16_t* __restrict__ Bt,
                                              void* __restrict__ C0, void* __restrict__ C1,
                                              int M, int N, int K) {
  constexpr int BM = 128, BN = 128, BK = 32;
  __shared__ bf16_t a_sh[BM * BK];
  __shared__ bf16_t b_sh[BN * BK];
  const int tid = threadIdx.x;
  const int wave = tid >> 6, lane = tid & 63;
  const int g = lane >> 4, lr = lane & 15;
  const int wm = wave >> 1, wn = wave & 1;
  const int m0 = blockIdx.y * BM, n0 = blockIdx.x * BN;
  const bf16_t* Ab = A + (size_t)m0 * K;
  const bf16_t* Bb = Bt + (size_t)n0 * K;

  f32x4 acc[4][4];
#pragma unroll
  for (int i = 0; i < 4; i++)
#pragma unroll
    for (int j = 0; j < 4; j++) acc[i][j] = (f32x4){0.f, 0.f, 0.f, 0.f};

  for (int k0 = 0; k0 < K; k0 += BK) {
#pragma unroll
    for (int i = 0; i < 2; i++) {
      int c = tid + 256 * i;
      gl_lds16(Ab + (size_t)(c >> 2) * K + k0 + (c & 3) * 8, &a_sh[c * 8]);
    }
#pragma unroll
    for (int i = 0; i < 2; i++) {
      int c = tid + 256 * i;
      gl_lds16(Bb + (size_t)(c >> 2) * K + k0 + (c & 3) * 8, &b_sh[c * 8]);
    }
    __syncthreads();
    bf16x8 af[4], bfr[4];
#pragma unroll
    for (int mi = 0; mi < 4; mi++)
      af[mi] = *reinterpret_cast<const bf16x8*>(&a_sh[(wm * 64 + mi * 16 + lr) * BK + g * 8]);
#pragma unroll
    for (int ni = 0; ni < 4; ni++)
      bfr[ni] = *reinterpret_cast<const bf16x8*>(&b_sh[(wn * 64 + ni * 16 + lr) * BK + g * 8]);
#pragma unroll
    for (int mi = 0; mi < 4; mi++)
#pragma unroll
      for (int ni = 0; ni < 4; ni++) acc[mi][ni] = mfma16(af[mi], bfr[ni], acc[mi][ni]);
    __syncthreads();
  }

#pragma unroll
  for (int mi = 0; mi < 4; mi++) {
#pragma unroll
    for (int ni = 0; ni < 4; ni++) {
      const int mb = m0 + wm * 64 + mi * 16 + g * 4;
      const int nb = n0 + wn * 64 + ni * 16;  // wave-uniform 16-col tile base
      if constexpr (MODE == 2) {
        float* C = (float*)C0;
#pragma unroll
        for (int r = 0; r < 4; r++) C[(size_t)(mb + r) * N + nb + lr] = acc[mi][ni][r];
      } else {
        if (nb < 2048) {
          bf16_t* qk = (bf16_t*)C0;
#pragma unroll
          for (int r = 0; r < 4; r++)
            qk[(size_t)(mb + r) * 2048 + nb + lr] = (bf16_t)acc[mi][ni][r];
        } else {
          bf16_t* vT = (bf16_t*)C1;  // [B*H][64][2048]
          const int b = mb >> 11, t = mb & 2047;
          const int col = nb - 2048 + lr;
          const int h = col >> 6, d = col & 63;
          bf16x4 o;
#pragma unroll
          for (int r = 0; r < 4; r++) o[r] = (bf16_t)acc[mi][ni][r];
          *reinterpret_cast<bf16x4*>(&vT[((size_t)(b * 16 + h) * 64 + d) * 2048 + t]) = o;
        }
      }
    }
  }
}

// ---------------- causal flash attention, bf16 MFMA ----------------
// qk: [B*T][2048] (Q cols 0..1023, K cols 1024..2047, head-major d)
// vT: [B*H][64][2048]   out: [B*T][1024]
__global__ __launch_bounds__(256) void k_attn(const bf16_t* __restrict__ qk,
                                              const bf16_t* __restrict__ vT,
                                              bf16_t* __restrict__ out) {
  constexpr int T = 2048;
  __shared__ bf16_t k_sh[64 * 64];
  __shared__ bf16_t v_sh[64 * 64];
  __shared__ bf16_t p_sh[4][16 * 72];
  const int tid = threadIdx.x;
  const int wave = tid >> 6, lane = tid & 63;
  const int g = lane >> 4, lr = lane & 15;
  const int qt = (int)gridDim.x - 1 - (int)blockIdx.x;  // heavy tiles first
  const int bh = blockIdx.y;
  const int b = bh >> 4, h = bh & 15;
  const int q0 = qt * 64 + wave * 16;

  // Q fragments held in registers (lane lr = A-operand row)
  bf16x8 qf[2];
  {
    const bf16_t* Qr = qk + (size_t)(b * T + q0 + lr) * 2048 + h * 64;
    qf[0] = *reinterpret_cast<const bf16x8*>(Qr + g * 8);
    qf[1] = *reinterpret_cast<const bf16x8*>(Qr + 32 + g * 8);
  }

  f32x4 acc_o[4];
#pragma unroll
  for (int i = 0; i < 4; i++) acc_o[i] = (f32x4){0.f, 0.f, 0.f, 0.f};
  float mrow[4] = {-__builtin_inff(), -__builtin_inff(), -__builtin_inff(), -__builtin_inff()};
  float lrow[4] = {0.f, 0.f, 0.f, 0.f};
  const int qtbase = qt * 64;

  for (int kv0 = 0; kv0 <= qtbase; kv0 += 64) {
    // stage K tile [64 kk][64 d] and V^T tile [64 d][64 kk], XOR-swizzled 16B slots
#pragma unroll
    for (int i = 0; i < 2; i++) {
      int c = tid + 256 * i;
      int row = c >> 3;
      int col8 = (c & 7) ^ (row & 7);
      gl_lds16(qk + (size_t)(b * T + kv0 + row) * 2048 + 1024 + h * 64 + col8 * 8, &k_sh[c * 8]);
    }
#pragma unroll
    for (int i = 0; i < 2; i++) {
      int c = tid + 256 * i;
      int d = c >> 3;
      int col8 = (c & 7) ^ (d & 7);
      gl_lds16(vT + ((size_t)bh * 64 + d) * T + kv0 + col8 * 8, &v_sh[c * 8]);
    }
    __syncthreads();

    // S[q][kk]: D[row=g*4+r][col=lr], per kt-tile of 16 kk
    f32x4 s[4];
#pragma unroll
    for (int kt = 0; kt < 4; kt++) {
      f32x4 a = (f32x4){0.f, 0.f, 0.f, 0.f};
      const int row = kt * 16 + lr;
      const int sw = row & 7;
      bf16x8 kf0 = *reinterpret_cast<const bf16x8*>(&k_sh[row * 64 + (g ^ sw) * 8]);
      a = mfma16(qf[0], kf0, a);
      bf16x8 kf1 = *reinterpret_cast<const bf16x8*>(&k_sh[row * 64 + ((4 + g) ^ sw) * 8]);
      a = mfma16(qf[1], kf1, a);
      s[kt] = a;
    }
    const float sc = 0.125f * LOG2E;  // d_k^-0.5, folded with log2(e) for exp2
#pragma unroll
    for (int kt = 0; kt < 4; kt++) s[kt] *= sc;
    if (kv0 == qtbase) {  // diagonal tile: causal mask
#pragma unroll
      for (int kt = 0; kt < 4; kt++)
#pragma unroll
        for (int r = 0; r < 4; r++)
          if (kv0 + kt * 16 + lr > q0 + g * 4 + r) s[kt][r] = -1e30f;
    }

    // online softmax (log2 domain)
    float rmax[4];
#pragma unroll
    for (int r = 0; r < 4; r++)
      rmax[r] = fmaxf(fmaxf(s[0][r], s[1][r]), fmaxf(s[2][r], s[3][r]));
#pragma unroll
    for (int off = 1; off < 16; off <<= 1)
#pragma unroll
      for (int r = 0; r < 4; r++) rmax[r] = fmaxf(rmax[r], __shfl_xor(rmax[r], off, 64));
    float mnew[4], alpha[4];
#pragma unroll
    for (int r = 0; r < 4; r++) {
      mnew[r] = fmaxf(mrow[r], rmax[r]);
      alpha[r] = __builtin_amdgcn_exp2f(mrow[r] - mnew[r]);
      mrow[r] = mnew[r];
    }
    float rs[4] = {0.f, 0.f, 0.f, 0.f};
#pragma unroll
    for (int kt = 0; kt < 4; kt++) {
#pragma unroll
      for (int r = 0; r < 4; r++) {
        float p = __builtin_amdgcn_exp2f(s[kt][r] - mnew[r]);
        rs[r] += p;
        p_sh[wave][(g * 4 + r) * 72 + kt * 16 + lr] = (bf16_t)p;
      }
    }
#pragma unroll
    for (int off = 1; off < 16; off <<= 1)
#pragma unroll
      for (int r = 0; r < 4; r++) rs[r] += __shfl_xor(rs[r], off, 64);
#pragma unroll
    for (int r = 0; r < 4; r++) lrow[r] = lrow[r] * alpha[r] + rs[r];
#pragma unroll
    for (int dt = 0; dt < 4; dt++)
#pragma unroll
      for (int r = 0; r < 4; r++) acc_o[dt][r] *= alpha[r];

    // PV: A = P (via per-wave LDS transpose), B = V (from swizzled V^T tile)
    bf16x8 pa0 = *reinterpret_cast<const bf16x8*>(&p_sh[wave][lr * 72 + g * 8]);
    bf16x8 pa1 = *reinterpret_cast<const bf16x8*>(&p_sh[wave][lr * 72 + 32 + g * 8]);
#pragma unroll
    for (int dt = 0; dt < 4; dt++) {
      const int drow = dt * 16 + lr;
      const int sw = drow & 7;
      bf16x8 v0 = *reinterpret_cast<const bf16x8*>(&v_sh[drow * 64 + (g ^ sw) * 8]);
      acc_o[dt] = mfma16(pa0, v0, acc_o[dt]);
      bf16x8 v1 = *reinterpret_cast<const bf16x8*>(&v_sh[drow * 64 + ((4 + g) ^ sw) * 8]);
      acc_o[dt] = mfma16(pa1, v1, acc_o[dt]);
    }
    __syncthreads();
  }

#pragma unroll
  for (int r = 0; r < 4; r++) {
    const float inv = 1.0f / lrow[r];
#pragma unroll
    for (int dt = 0; dt < 4; dt++)
      out[(size_t)(b * T + q0 + g * 4 + r) * 1024 + h * 64 + dt * 16 + lr] =
          (bf16_t)(acc_o[dt][r] * inv);
  }
}

extern "C" void kernel_launch(void* const* d_in, const int* in_sizes, int n_in,
                              void* d_out, int out_size, void* d_ws, size_t ws_size,
                              hipStream_t stream) {
  (void)in_sizes; (void)n_in; (void)out_size; (void)ws_size;
  const float* x = (const float*)d_in[0];
  const float* w_qkv = (const float*)d_in[1];
  const float* w_out = (const float*)d_in[2];
  float* out = (float*)d_out;
  const int T = 2048, C = 1024;
  const int M = 4 * T;  // 8192

  // workspace layout (bf16), ~92 MB total
  bf16_t* xb = (bf16_t*)d_ws;                    // [M][C]
  bf16_t* wqkvT = xb + (size_t)M * C;            // [3C][C]
  bf16_t* woutT = wqkvT + (size_t)3 * C * C;     // [C][C]
  bf16_t* qkbuf = woutT + (size_t)C * C;         // [M][2C]
  bf16_t* vT = qkbuf + (size_t)M * 2 * C;        // [B*H][64][T]
  bf16_t* attn = vT + (size_t)M * C;             // [M][C]

  k_cvt_bf16<<<2048, 256, 0, stream>>>(x, xb, M * C / 4);
  k_transpose_cvt<<<dim3(3 * C / 64, C / 64), 256, 0, stream>>>(w_qkv, wqkvT, C, 3 * C);
  k_transpose_cvt<<<dim3(C / 64, C / 64), 256, 0, stream>>>(w_out, woutT, C, C);
  k_gemm<1><<<dim3(3 * C / 128, M / 128), 256, 0, stream>>>(xb, wqkvT, qkbuf, vT, M, 3 * C, C);
  k_attn<<<dim3(T / 64, 64), 256, 0, stream>>>(qkbuf, vT, attn);
  k_gemm<2><<<dim3(C / 128, M / 128), 256, 0, stream>>>(attn, woutT, out, nullptr, M, C, C);
}

// Round 2
// 315.903 us; speedup vs baseline: 1.2537x; 1.2537x over previous
//
#include <hip/hip_runtime.h>
#include <stdint.h>

// B=4, T=2048, C=1024, H=16, d_k=64. fp32 in/out, bf16 MFMA compute.

typedef __bf16 bf16_t;
typedef __bf16 bf16x4 __attribute__((ext_vector_type(4)));
typedef __bf16 bf16x8 __attribute__((ext_vector_type(8)));
typedef float f32x4 __attribute__((ext_vector_type(4)));

#define LOG2E 1.44269504088896340736f

__device__ __forceinline__ void gl_lds16(const void* g, void* l) {
  __builtin_amdgcn_global_load_lds(
      (const __attribute__((address_space(1))) unsigned int*)g,
      (__attribute__((address_space(3))) unsigned int*)l, 16, 0, 0);
}

__device__ __forceinline__ f32x4 mfma16(bf16x8 a, bf16x8 b, f32x4 c) {
  return __builtin_amdgcn_mfma_f32_16x16x32_bf16(a, b, c, 0, 0, 0);
}

// ---------------- fp32 -> bf16 vectorized convert ----------------
__global__ __launch_bounds__(256) void k_cvt_bf16(const float* __restrict__ in,
                                                  bf16_t* __restrict__ out, int n4) {
  int i = blockIdx.x * 256 + threadIdx.x;
  int step = gridDim.x * 256;
  for (; i < n4; i += step) {
    f32x4 v = reinterpret_cast<const f32x4*>(in)[i];
    bf16x4 o;
    o[0] = (bf16_t)v[0]; o[1] = (bf16_t)v[1];
    o[2] = (bf16_t)v[2]; o[3] = (bf16_t)v[3];
    reinterpret_cast<bf16x4*>(out)[i] = o;
  }
}

// ------------- fp32 [R][Cc] -> bf16 [Cc][R] tiled transpose -------------
__global__ __launch_bounds__(256) void k_transpose_cvt(const float* __restrict__ in,
                                                       bf16_t* __restrict__ out,
                                                       int R, int Cc) {
  __shared__ float tile[64][65];
  const int tid = threadIdx.x;
  const int c0 = blockIdx.x * 64, r0 = blockIdx.y * 64;
  const int rr = tid >> 4, cc = (tid & 15) * 4;
#pragma unroll
  for (int i = 0; i < 4; i++) {
    f32x4 v = *reinterpret_cast<const f32x4*>(&in[(size_t)(r0 + rr + i * 16) * Cc + c0 + cc]);
    tile[rr + i * 16][cc + 0] = v[0];
    tile[rr + i * 16][cc + 1] = v[1];
    tile[rr + i * 16][cc + 2] = v[2];
    tile[rr + i * 16][cc + 3] = v[3];
  }
  __syncthreads();
  const int cr = tid >> 2, kb = (tid & 3) * 16;
#pragma unroll
  for (int j4 = 0; j4 < 4; j4++) {
    bf16x4 o;
#pragma unroll
    for (int jj = 0; jj < 4; jj++) o[jj] = (bf16_t)tile[kb + j4 * 4 + jj][cr];
    *reinterpret_cast<bf16x4*>(&out[(size_t)(c0 + cr) * R + r0 + kb + j4 * 4]) = o;
  }
}

// ---------------- bf16 GEMM: C[M][N] = A[M][K] * Bt[N][K]^T ----------------
template <int MODE>
__global__ __launch_bounds__(256) void k_gemm(const bf16_t* __restrict__ A,
                                              const bf16_t* __restrict__ Bt,
                                              void* __restrict__ C0, void* __restrict__ C1,
                                              int M, int N, int K) {
  constexpr int BM = 128, BN = 128, BK = 32;
  __shared__ bf16_t a_sh[BM * BK];
  __shared__ bf16_t b_sh[BN * BK];
  const int tid = threadIdx.x;
  const int wave = tid >> 6, lane = tid & 63;
  const int g = lane >> 4, lr = lane & 15;
  const int wm = wave >> 1, wn = wave & 1;
  const int m0 = blockIdx.y * BM, n0 = blockIdx.x * BN;
  const bf16_t* Ab = A + (size_t)m0 * K;
  const bf16_t* Bb = Bt + (size_t)n0 * K;

  f32x4 acc[4][4];
#pragma unroll
  for (int i = 0; i < 4; i++)
#pragma unroll
    for (int j = 0; j < 4; j++) acc[i][j] = (f32x4){0.f, 0.f, 0.f, 0.f};

  for (int k0 = 0; k0 < K; k0 += BK) {
#pragma unroll
    for (int i = 0; i < 2; i++) {
      int c = tid + 256 * i;
      gl_lds16(Ab + (size_t)(c >> 2) * K + k0 + (c & 3) * 8, &a_sh[c * 8]);
    }
#pragma unroll
    for (int i = 0; i < 2; i++) {
      int c = tid + 256 * i;
      gl_lds16(Bb + (size_t)(c >> 2) * K + k0 + (c & 3) * 8, &b_sh[c * 8]);
    }
    __syncthreads();
    bf16x8 af[4], bfr[4];
#pragma unroll
    for (int mi = 0; mi < 4; mi++)
      af[mi] = *reinterpret_cast<const bf16x8*>(&a_sh[(wm * 64 + mi * 16 + lr) * BK + g * 8]);
#pragma unroll
    for (int ni = 0; ni < 4; ni++)
      bfr[ni] = *reinterpret_cast<const bf16x8*>(&b_sh[(wn * 64 + ni * 16 + lr) * BK + g * 8]);
#pragma unroll
    for (int mi = 0; mi < 4; mi++)
#pragma unroll
      for (int ni = 0; ni < 4; ni++) acc[mi][ni] = mfma16(af[mi], bfr[ni], acc[mi][ni]);
    __syncthreads();
  }

#pragma unroll
  for (int mi = 0; mi < 4; mi++) {
#pragma unroll
    for (int ni = 0; ni < 4; ni++) {
      const int mb = m0 + wm * 64 + mi * 16 + g * 4;
      const int nb = n0 + wn * 64 + ni * 16;
      if constexpr (MODE == 2) {
        float* C = (float*)C0;
#pragma unroll
        for (int r = 0; r < 4; r++) C[(size_t)(mb + r) * N + nb + lr] = acc[mi][ni][r];
      } else {
        if (nb < 2048) {
          bf16_t* qk = (bf16_t*)C0;
#pragma unroll
          for (int r = 0; r < 4; r++)
            qk[(size_t)(mb + r) * 2048 + nb + lr] = (bf16_t)acc[mi][ni][r];
        } else {
          bf16_t* vT = (bf16_t*)C1;  // [B*H][64][2048]
          const int b = mb >> 11, t = mb & 2047;
          const int col = nb - 2048 + lr;
          const int h = col >> 6, d = col & 63;
          bf16x4 o;
#pragma unroll
          for (int r = 0; r < 4; r++) o[r] = (bf16_t)acc[mi][ni][r];
          *reinterpret_cast<bf16x4*>(&vT[((size_t)(b * 16 + h) * 64 + d) * 2048 + t]) = o;
        }
      }
    }
  }
}

// ---------------- causal flash attention, bf16 MFMA ----------------
// QBLK=128/block (4 waves x 32 rows), KVBLK=64, double-buffered K/V staging,
// XOR-swizzled LDS, bh-locality XCD swizzle.
// qk: [B*T][2048] (Q cols 0..1023, K cols 1024..2047, head-major d)
// vT: [B*H][64][2048]   out: [B*T][1024] bf16
__global__ __launch_bounds__(256) void k_attn(const bf16_t* __restrict__ qk,
                                              const bf16_t* __restrict__ vT,
                                              bf16_t* __restrict__ out) {
  constexpr int T = 2048;
  __shared__ bf16_t k_sh[2][64 * 64];
  __shared__ bf16_t v_sh[2][64 * 64];
  __shared__ bf16_t p_sh[4][32 * 72];
  const int tid = threadIdx.x;
  const int wave = tid >> 6, lane = tid & 63;
  const int g = lane >> 4, lr = lane & 15;

  // XCD swizzle: 1024 blocks; xcd = flat%8 owns bh in [xcd*8, xcd*8+8); qt heavy-first
  const int flat = blockIdx.x;
  const int qt = 15 - (flat >> 6);
  const int s6 = flat & 63;
  const int bh = (s6 & 7) * 8 + (s6 >> 3);
  const int b = bh >> 4, h = bh & 15;
  const int q0w = qt * 128 + wave * 32;

  // Q fragments in registers: rows q0w + rb*16 + lr, d halves
  bf16x8 qf[2][2];
#pragma unroll
  for (int rb = 0; rb < 2; rb++) {
    const bf16_t* Qr = qk + (size_t)(b * T + q0w + rb * 16 + lr) * 2048 + h * 64;
    qf[rb][0] = *reinterpret_cast<const bf16x8*>(Qr + g * 8);
    qf[rb][1] = *reinterpret_cast<const bf16x8*>(Qr + 32 + g * 8);
  }

  f32x4 acc_o[2][4];
#pragma unroll
  for (int rb = 0; rb < 2; rb++)
#pragma unroll
    for (int dt = 0; dt < 4; dt++) acc_o[rb][dt] = (f32x4){0.f, 0.f, 0.f, 0.f};
  float mrow[2][4], lrow[2][4];
#pragma unroll
  for (int rb = 0; rb < 2; rb++)
#pragma unroll
    for (int r = 0; r < 4; r++) { mrow[rb][r] = -__builtin_inff(); lrow[rb][r] = 0.f; }

  const int nt = 2 * qt + 2;
  const bf16_t* Kbase = qk + (size_t)b * T * 2048 + 1024 + h * 64;
  const bf16_t* Vbase = vT + (size_t)bh * 64 * T;

  // prologue: stage tile 0 into buf 0
  {
#pragma unroll
    for (int i = 0; i < 2; i++) {
      int c = tid + 256 * i;
      int row = c >> 3, col8 = (c & 7) ^ (row & 7);
      gl_lds16(Kbase + (size_t)row * 2048 + col8 * 8, &k_sh[0][c * 8]);
    }
#pragma unroll
    for (int i = 0; i < 2; i++) {
      int c = tid + 256 * i;
      int d = c >> 3, col8 = (c & 7) ^ (d & 7);
      gl_lds16(Vbase + (size_t)d * T + col8 * 8, &v_sh[0][c * 8]);
    }
  }
  __syncthreads();

  int cur = 0;
  for (int t = 0; t < nt; ++t) {
    const int kv0 = t * 64;
    // prefetch next tile into other buffer (overlaps with compute below)
    if (t + 1 < nt) {
      const int kn = kv0 + 64;
#pragma unroll
      for (int i = 0; i < 2; i++) {
        int c = tid + 256 * i;
        int row = c >> 3, col8 = (c & 7) ^ (row & 7);
        gl_lds16(Kbase + (size_t)(kn + row) * 2048 + col8 * 8, &k_sh[cur ^ 1][c * 8]);
      }
#pragma unroll
      for (int i = 0; i < 2; i++) {
        int c = tid + 256 * i;
        int d = c >> 3, col8 = (c & 7) ^ (d & 7);
        gl_lds16(Vbase + (size_t)d * T + kn + col8 * 8, &v_sh[cur ^ 1][c * 8]);
      }
    }

    // ---- QK^T: S[rb][kt] = D[row=g*4+r][col=lr] over kk tiles ----
    f32x4 s[2][4];
#pragma unroll
    for (int rb = 0; rb < 2; rb++)
#pragma unroll
      for (int kt = 0; kt < 4; kt++) s[rb][kt] = (f32x4){0.f, 0.f, 0.f, 0.f};
    __builtin_amdgcn_s_setprio(1);
#pragma unroll
    for (int kt = 0; kt < 4; kt++) {
      const int row = kt * 16 + lr, sw = row & 7;
      bf16x8 kf0 = *reinterpret_cast<const bf16x8*>(&k_sh[cur][row * 64 + (g ^ sw) * 8]);
      bf16x8 kf1 = *reinterpret_cast<const bf16x8*>(&k_sh[cur][row * 64 + ((4 + g) ^ sw) * 8]);
#pragma unroll
      for (int rb = 0; rb < 2; rb++) {
        s[rb][kt] = mfma16(qf[rb][0], kf0, s[rb][kt]);
        s[rb][kt] = mfma16(qf[rb][1], kf1, s[rb][kt]);
      }
    }
    __builtin_amdgcn_s_setprio(0);

    const float sc = 0.125f * LOG2E;
#pragma unroll
    for (int rb = 0; rb < 2; rb++)
#pragma unroll
      for (int kt = 0; kt < 4; kt++) s[rb][kt] *= sc;
    if (kv0 + 63 > q0w) {  // tile may touch the causal boundary for this wave
#pragma unroll
      for (int rb = 0; rb < 2; rb++)
#pragma unroll
        for (int kt = 0; kt < 4; kt++)
#pragma unroll
          for (int r = 0; r < 4; r++)
            if (kv0 + kt * 16 + lr > q0w + rb * 16 + g * 4 + r) s[rb][kt][r] = -1e30f;
    }

    // ---- online softmax (log2 domain) ----
#pragma unroll
    for (int rb = 0; rb < 2; rb++) {
      float rmax[4];
#pragma unroll
      for (int r = 0; r < 4; r++)
        rmax[r] = fmaxf(fmaxf(s[rb][0][r], s[rb][1][r]), fmaxf(s[rb][2][r], s[rb][3][r]));
#pragma unroll
      for (int off = 1; off < 16; off <<= 1)
#pragma unroll
        for (int r = 0; r < 4; r++) rmax[r] = fmaxf(rmax[r], __shfl_xor(rmax[r], off, 64));
      float mnew[4], alpha[4];
#pragma unroll
      for (int r = 0; r < 4; r++) {
        mnew[r] = fmaxf(mrow[rb][r], rmax[r]);
        alpha[r] = __builtin_amdgcn_exp2f(mrow[rb][r] - mnew[r]);
        mrow[rb][r] = mnew[r];
      }
      float rs[4] = {0.f, 0.f, 0.f, 0.f};
#pragma unroll
      for (int kt = 0; kt < 4; kt++) {
#pragma unroll
        for (int r = 0; r < 4; r++) {
          float p = __builtin_amdgcn_exp2f(s[rb][kt][r] - mnew[r]);
          rs[r] += p;
          p_sh[wave][(rb * 16 + g * 4 + r) * 72 + kt * 16 + lr] = (bf16_t)p;
        }
      }
#pragma unroll
      for (int off = 1; off < 16; off <<= 1)
#pragma unroll
        for (int r = 0; r < 4; r++) rs[r] += __shfl_xor(rs[r], off, 64);
#pragma unroll
      for (int r = 0; r < 4; r++) lrow[rb][r] = lrow[rb][r] * alpha[r] + rs[r];
#pragma unroll
      for (int dt = 0; dt < 4; dt++)
#pragma unroll
        for (int r = 0; r < 4; r++) acc_o[rb][dt][r] *= alpha[r];
    }

    // ---- PV: A = P (LDS transpose), B = V^T rows (swizzled) ----
    bf16x8 pa[2][2];
#pragma unroll
    for (int rb = 0; rb < 2; rb++) {
      pa[rb][0] = *reinterpret_cast<const bf16x8*>(&p_sh[wave][(rb * 16 + lr) * 72 + g * 8]);
      pa[rb][1] = *reinterpret_cast<const bf16x8*>(&p_sh[wave][(rb * 16 + lr) * 72 + 32 + g * 8]);
    }
    __builtin_amdgcn_s_setprio(1);
#pragma unroll
    for (int dt = 0; dt < 4; dt++) {
      const int drow = dt * 16 + lr, sw = drow & 7;
      bf16x8 v0 = *reinterpret_cast<const bf16x8*>(&v_sh[cur][drow * 64 + (g ^ sw) * 8]);
      bf16x8 v1 = *reinterpret_cast<const bf16x8*>(&v_sh[cur][drow * 64 + ((4 + g) ^ sw) * 8]);
#pragma unroll
      for (int rb = 0; rb < 2; rb++) {
        acc_o[rb][dt] = mfma16(pa[rb][0], v0, acc_o[rb][dt]);
        acc_o[rb][dt] = mfma16(pa[rb][1], v1, acc_o[rb][dt]);
      }
    }
    __builtin_amdgcn_s_setprio(0);

    __syncthreads();  // drains prefetch vmcnt + guards LDS buffer swap
    cur ^= 1;
  }

#pragma unroll
  for (int rb = 0; rb < 2; rb++)
#pragma unroll
    for (int r = 0; r < 4; r++) {
      const float inv = 1.0f / lrow[rb][r];
#pragma unroll
      for (int dt = 0; dt < 4; dt++)
        out[(size_t)(b * T + q0w + rb * 16 + g * 4 + r) * 1024 + h * 64 + dt * 16 + lr] =
            (bf16_t)(acc_o[rb][dt][r] * inv);
    }
}

extern "C" void kernel_launch(void* const* d_in, const int* in_sizes, int n_in,
                              void* d_out, int out_size, void* d_ws, size_t ws_size,
                              hipStream_t stream) {
  (void)in_sizes; (void)n_in; (void)out_size; (void)ws_size;
  const float* x = (const float*)d_in[0];
  const float* w_qkv = (const float*)d_in[1];
  const float* w_out = (const float*)d_in[2];
  float* out = (float*)d_out;
  const int T = 2048, C = 1024;
  const int M = 4 * T;  // 8192

  bf16_t* xb = (bf16_t*)d_ws;                    // [M][C]
  bf16_t* wqkvT = xb + (size_t)M * C;            // [3C][C]
  bf16_t* woutT = wqkvT + (size_t)3 * C * C;     // [C][C]
  bf16_t* qkbuf = woutT + (size_t)C * C;         // [M][2C]
  bf16_t* vT = qkbuf + (size_t)M * 2 * C;        // [B*H][64][T]
  bf16_t* attn = vT + (size_t)M * C;             // [M][C]

  k_cvt_bf16<<<2048, 256, 0, stream>>>(x, xb, M * C / 4);
  k_transpose_cvt<<<dim3(3 * C / 64, C / 64), 256, 0, stream>>>(w_qkv, wqkvT, C, 3 * C);
  k_transpose_cvt<<<dim3(C / 64, C / 64), 256, 0, stream>>>(w_out, woutT, C, C);
  k_gemm<1><<<dim3(3 * C / 128, M / 128), 256, 0, stream>>>(xb, wqkvT, qkbuf, vT, M, 3 * C, C);
  k_attn<<<1024, 256, 0, stream>>>(qkbuf, vT, attn);
  k_gemm<2><<<dim3(C / 128, M / 128), 256, 0, stream>>>(attn, woutT, out, nullptr, M, C, C);
}

// Round 3
// 256.174 us; speedup vs baseline: 1.5460x; 1.2332x over previous
//
#include <hip/hip_runtime.h>
#include <stdint.h>

// B=4, T=2048, C=1024, H=16, d_k=64. fp32 in/out, bf16 MFMA compute.

typedef __bf16 bf16_t;
typedef __bf16 bf16x4 __attribute__((ext_vector_type(4)));
typedef __bf16 bf16x8 __attribute__((ext_vector_type(8)));
typedef float f32x4 __attribute__((ext_vector_type(4)));

#define LOG2E 1.44269504088896340736f
#define QSCALE (0.125f * LOG2E)  // folded into Q at GEMM1 epilogue

__device__ __forceinline__ void gl_lds16(const void* g, void* l) {
  __builtin_amdgcn_global_load_lds(
      (const __attribute__((address_space(1))) unsigned int*)g,
      (__attribute__((address_space(3))) unsigned int*)l, 16, 0, 0);
}

__device__ __forceinline__ f32x4 mfma16(bf16x8 a, bf16x8 b, f32x4 c) {
  return __builtin_amdgcn_mfma_f32_16x16x32_bf16(a, b, c, 0, 0, 0);
}

// ---------------- fp32 -> bf16 vectorized convert ----------------
__global__ __launch_bounds__(256) void k_cvt_bf16(const float* __restrict__ in,
                                                  bf16_t* __restrict__ out, int n4) {
  int i = blockIdx.x * 256 + threadIdx.x;
  int step = gridDim.x * 256;
  for (; i < n4; i += step) {
    f32x4 v = reinterpret_cast<const f32x4*>(in)[i];
    bf16x4 o;
    o[0] = (bf16_t)v[0]; o[1] = (bf16_t)v[1];
    o[2] = (bf16_t)v[2]; o[3] = (bf16_t)v[3];
    reinterpret_cast<bf16x4*>(out)[i] = o;
  }
}

// ------------- fp32 [R][Cc] -> bf16 [Cc][R] tiled transpose -------------
__global__ __launch_bounds__(256) void k_transpose_cvt(const float* __restrict__ in,
                                                       bf16_t* __restrict__ out,
                                                       int R, int Cc) {
  __shared__ float tile[64][65];
  const int tid = threadIdx.x;
  const int c0 = blockIdx.x * 64, r0 = blockIdx.y * 64;
  const int rr = tid >> 4, cc = (tid & 15) * 4;
#pragma unroll
  for (int i = 0; i < 4; i++) {
    f32x4 v = *reinterpret_cast<const f32x4*>(&in[(size_t)(r0 + rr + i * 16) * Cc + c0 + cc]);
    tile[rr + i * 16][cc + 0] = v[0];
    tile[rr + i * 16][cc + 1] = v[1];
    tile[rr + i * 16][cc + 2] = v[2];
    tile[rr + i * 16][cc + 3] = v[3];
  }
  __syncthreads();
  const int cr = tid >> 2, kb = (tid & 3) * 16;
#pragma unroll
  for (int j4 = 0; j4 < 4; j4++) {
    bf16x4 o;
#pragma unroll
    for (int jj = 0; jj < 4; jj++) o[jj] = (bf16_t)tile[kb + j4 * 4 + jj][cr];
    *reinterpret_cast<bf16x4*>(&out[(size_t)(c0 + cr) * R + r0 + kb + j4 * 4]) = o;
  }
}

// ---------------- bf16 GEMM: C[M][N] = A[M][K] * Bt[N][K]^T ----------------
// 2-phase double-buffered staging (one barrier per K-step), XCD-swizzled grid.
// MODE 1: QKV epilogue -> Q (scaled by QSCALE) + K to qk[M][2048]; V to vT
// MODE 2: fp32 C[M][N]
template <int MODE>
__global__ __launch_bounds__(256) void k_gemm(const bf16_t* __restrict__ A,
                                              const bf16_t* __restrict__ Bt,
                                              void* __restrict__ C0, void* __restrict__ C1,
                                              int M, int N, int K, int nbx) {
  constexpr int BM = 128, BN = 128, BK = 32;
  __shared__ bf16_t a_sh[2][BM * BK];
  __shared__ bf16_t b_sh[2][BN * BK];
  const int tid = threadIdx.x;
  const int wave = tid >> 6, lane = tid & 63;
  const int g = lane >> 4, lr = lane & 15;
  const int wm = wave >> 1, wn = wave & 1;
  // XCD swizzle (gridDim.x divisible by 8)
  const int nblk = gridDim.x;
  const int swid = (blockIdx.x & 7) * (nblk >> 3) + (blockIdx.x >> 3);
  const int m0 = (swid / nbx) * BM, n0 = (swid % nbx) * BN;
  const bf16_t* Ab = A + (size_t)m0 * K;
  const bf16_t* Bb = Bt + (size_t)n0 * K;

  f32x4 acc[4][4];
#pragma unroll
  for (int i = 0; i < 4; i++)
#pragma unroll
    for (int j = 0; j < 4; j++) acc[i][j] = (f32x4){0.f, 0.f, 0.f, 0.f};

  auto stage = [&](int buf, int k0) {
#pragma unroll
    for (int i = 0; i < 2; i++) {
      int c = tid + 256 * i;
      gl_lds16(Ab + (size_t)(c >> 2) * K + k0 + (c & 3) * 8, &a_sh[buf][c * 8]);
    }
#pragma unroll
    for (int i = 0; i < 2; i++) {
      int c = tid + 256 * i;
      gl_lds16(Bb + (size_t)(c >> 2) * K + k0 + (c & 3) * 8, &b_sh[buf][c * 8]);
    }
  };

  stage(0, 0);
  __syncthreads();
  int cur = 0;
  for (int k0 = 0; k0 < K; k0 += BK) {
    if (k0 + BK < K) stage(cur ^ 1, k0 + BK);
    bf16x8 af[4], bfr[4];
#pragma unroll
    for (int mi = 0; mi < 4; mi++)
      af[mi] = *reinterpret_cast<const bf16x8*>(&a_sh[cur][(wm * 64 + mi * 16 + lr) * BK + g * 8]);
#pragma unroll
    for (int ni = 0; ni < 4; ni++)
      bfr[ni] = *reinterpret_cast<const bf16x8*>(&b_sh[cur][(wn * 64 + ni * 16 + lr) * BK + g * 8]);
    __builtin_amdgcn_s_setprio(1);
#pragma unroll
    for (int mi = 0; mi < 4; mi++)
#pragma unroll
      for (int ni = 0; ni < 4; ni++) acc[mi][ni] = mfma16(af[mi], bfr[ni], acc[mi][ni]);
    __builtin_amdgcn_s_setprio(0);
    __syncthreads();
    cur ^= 1;
  }

#pragma unroll
  for (int mi = 0; mi < 4; mi++) {
#pragma unroll
    for (int ni = 0; ni < 4; ni++) {
      const int mb = m0 + wm * 64 + mi * 16 + g * 4;
      const int nb = n0 + wn * 64 + ni * 16;
      if constexpr (MODE == 2) {
        float* C = (float*)C0;
#pragma unroll
        for (int r = 0; r < 4; r++) C[(size_t)(mb + r) * N + nb + lr] = acc[mi][ni][r];
      } else {
        if (nb < 2048) {
          const float scl = (nb < 1024) ? QSCALE : 1.0f;  // fold softmax scale into Q
          bf16_t* qk = (bf16_t*)C0;
#pragma unroll
          for (int r = 0; r < 4; r++)
            qk[(size_t)(mb + r) * 2048 + nb + lr] = (bf16_t)(acc[mi][ni][r] * scl);
        } else {
          bf16_t* vT = (bf16_t*)C1;  // [B*H][64][2048]
          const int b = mb >> 11, t = mb & 2047;
          const int col = nb - 2048 + lr;
          const int h = col >> 6, d = col & 63;
          bf16x4 o;
#pragma unroll
          for (int r = 0; r < 4; r++) o[r] = (bf16_t)acc[mi][ni][r];
          *reinterpret_cast<bf16x4*>(&vT[((size_t)(b * 16 + h) * 64 + d) * 2048 + t]) = o;
        }
      }
    }
  }
}

// ---------------- causal flash attention, bf16 MFMA ----------------
// Swapped QK^T (D[k][q]) -> in-lane softmax; defer-max; packed P writes.
// qk: [B*T][2048] (Q cols 0..1023 pre-scaled, K cols 1024..2047)
// vT: [B*H][64][2048]   out: [B*T][1024] bf16
__global__ __launch_bounds__(256) void k_attn(const bf16_t* __restrict__ qk,
                                              const bf16_t* __restrict__ vT,
                                              bf16_t* __restrict__ out) {
  constexpr int T = 2048;
  constexpr int PST = 72;
  __shared__ bf16_t k_sh[2][64 * 64];
  __shared__ bf16_t v_sh[2][64 * 64];
  __shared__ bf16_t p_sh[4][32 * PST];
  const int tid = threadIdx.x;
  const int wave = tid >> 6, lane = tid & 63;
  const int g = lane >> 4, lr = lane & 15;

  const int flat = blockIdx.x;
  const int qt = 15 - (flat >> 6);
  const int s6 = flat & 63;
  const int bh = (s6 & 7) * 8 + (s6 >> 3);
  const int b = bh >> 4, h = bh & 15;
  const int q0w = qt * 128 + wave * 32;

  // Q fragments (B-operand): lane lr = q-row rb*16+lr
  bf16x8 qf[2][2];
#pragma unroll
  for (int rb = 0; rb < 2; rb++) {
    const bf16_t* Qr = qk + (size_t)(b * T + q0w + rb * 16 + lr) * 2048 + h * 64;
    qf[rb][0] = *reinterpret_cast<const bf16x8*>(Qr + g * 8);
    qf[rb][1] = *reinterpret_cast<const bf16x8*>(Qr + 32 + g * 8);
  }

  f32x4 acc_o[2][4];
#pragma unroll
  for (int rb = 0; rb < 2; rb++)
#pragma unroll
    for (int dt = 0; dt < 4; dt++) acc_o[rb][dt] = (f32x4){0.f, 0.f, 0.f, 0.f};
  // softmax state lives at q = rb*16 + (lane&15), replicated across g
  float mrow[2] = {-1e30f, -1e30f};
  float lrow[2] = {0.f, 0.f};

  const int nt = 2 * qt + 2;
  const bf16_t* Kbase = qk + (size_t)b * T * 2048 + 1024 + h * 64;
  const bf16_t* Vbase = vT + (size_t)bh * 64 * T;

  auto stageK = [&](int buf, int kv) {
#pragma unroll
    for (int i = 0; i < 2; i++) {
      int c = tid + 256 * i;
      int row = c >> 3, col8 = (c & 7) ^ (row & 7);
      gl_lds16(Kbase + (size_t)(kv + row) * 2048 + col8 * 8, &k_sh[buf][c * 8]);
    }
#pragma unroll
    for (int i = 0; i < 2; i++) {
      int c = tid + 256 * i;
      int d = c >> 3, col8 = (c & 7) ^ (d & 7);
      gl_lds16(Vbase + (size_t)d * T + kv + col8 * 8, &v_sh[buf][c * 8]);
    }
  };

  stageK(0, 0);
  __syncthreads();

  int cur = 0;
  for (int t = 0; t < nt; ++t) {
    const int kv0 = t * 64;
    if (t + 1 < nt) stageK(cur ^ 1, kv0 + 64);

    // ---- swapped QK^T: lane holds S[k = kv0+kt*16+g*4+r][q = q0w+rb*16+lr] ----
    f32x4 s[2][4];
#pragma unroll
    for (int rb = 0; rb < 2; rb++)
#pragma unroll
      for (int kt = 0; kt < 4; kt++) s[rb][kt] = (f32x4){0.f, 0.f, 0.f, 0.f};
    __builtin_amdgcn_s_setprio(1);
#pragma unroll
    for (int kt = 0; kt < 4; kt++) {
      const int row = kt * 16 + lr, sw = row & 7;
      bf16x8 kf0 = *reinterpret_cast<const bf16x8*>(&k_sh[cur][row * 64 + (g ^ sw) * 8]);
      bf16x8 kf1 = *reinterpret_cast<const bf16x8*>(&k_sh[cur][row * 64 + ((4 + g) ^ sw) * 8]);
#pragma unroll
      for (int rb = 0; rb < 2; rb++) {
        s[rb][kt] = mfma16(kf0, qf[rb][0], s[rb][kt]);
        s[rb][kt] = mfma16(kf1, qf[rb][1], s[rb][kt]);
      }
    }
    __builtin_amdgcn_s_setprio(0);

    if (kv0 + 63 > q0w) {  // causal mask on boundary tiles
#pragma unroll
      for (int rb = 0; rb < 2; rb++)
#pragma unroll
        for (int kt = 0; kt < 4; kt++)
#pragma unroll
          for (int r = 0; r < 4; r++)
            if (kv0 + kt * 16 + g * 4 + r > q0w + rb * 16 + lr) s[rb][kt][r] = -1e30f;
    }

    // ---- in-lane online softmax (log2 domain; Q pre-scaled) ----
#pragma unroll
    for (int rb = 0; rb < 2; rb++) {
      float pm = s[rb][0][0];
#pragma unroll
      for (int kt = 0; kt < 4; kt++)
#pragma unroll
        for (int r = 0; r < 4; r++) pm = fmaxf(pm, s[rb][kt][r]);
      pm = fmaxf(pm, __shfl_xor(pm, 16, 64));
      pm = fmaxf(pm, __shfl_xor(pm, 32, 64));

      // defer-max (T13): only rescale when max grew by > 8 (log2 units)
      unsigned long long need = __ballot(pm > mrow[rb] + 8.0f);
      if (need) {
        float mnew = fmaxf(mrow[rb], pm);
        float alpha = __builtin_amdgcn_exp2f(mrow[rb] - mnew);
        mrow[rb] = mnew;
        lrow[rb] *= alpha;
#pragma unroll
        for (int r = 0; r < 4; r++) {
          int src = (lane & 48) | ((lane >> 2) & 12) | r;  // lane of q-row g*4+r
          float ar = __shfl(alpha, src, 64);
#pragma unroll
          for (int dt = 0; dt < 4; dt++) acc_o[rb][dt][r] *= ar;
        }
      }

      float rs = 0.f;
#pragma unroll
      for (int kt = 0; kt < 4; kt++) {
        f32x4 p;
#pragma unroll
        for (int r = 0; r < 4; r++) p[r] = __builtin_amdgcn_exp2f(s[rb][kt][r] - mrow[rb]);
        rs += (p[0] + p[1]) + (p[2] + p[3]);
        bf16x4 pb;
#pragma unroll
        for (int r = 0; r < 4; r++) pb[r] = (bf16_t)p[r];
        *reinterpret_cast<bf16x4*>(&p_sh[wave][(rb * 16 + lr) * PST + kt * 16 + g * 4]) = pb;
      }
      rs += __shfl_xor(rs, 16, 64);
      rs += __shfl_xor(rs, 32, 64);
      lrow[rb] += rs;
    }

    // ---- PV: A = P (per-wave LDS transpose), B = V^T rows (swizzled) ----
    bf16x8 pa[2][2];
#pragma unroll
    for (int rb = 0; rb < 2; rb++) {
      pa[rb][0] = *reinterpret_cast<const bf16x8*>(&p_sh[wave][(rb * 16 + lr) * PST + g * 8]);
      pa[rb][1] = *reinterpret_cast<const bf16x8*>(&p_sh[wave][(rb * 16 + lr) * PST + 32 + g * 8]);
    }
    __builtin_amdgcn_s_setprio(1);
#pragma unroll
    for (int dt = 0; dt < 4; dt++) {
      const int drow = dt * 16 + lr, sw = drow & 7;
      bf16x8 v0 = *reinterpret_cast<const bf16x8*>(&v_sh[cur][drow * 64 + (g ^ sw) * 8]);
      bf16x8 v1 = *reinterpret_cast<const bf16x8*>(&v_sh[cur][drow * 64 + ((4 + g) ^ sw) * 8]);
#pragma unroll
      for (int rb = 0; rb < 2; rb++) {
        acc_o[rb][dt] = mfma16(pa[rb][0], v0, acc_o[rb][dt]);
        acc_o[rb][dt] = mfma16(pa[rb][1], v1, acc_o[rb][dt]);
      }
    }
    __builtin_amdgcn_s_setprio(0);

    __syncthreads();  // drains prefetch vmcnt + guards LDS buffer swap
    cur ^= 1;
  }

#pragma unroll
  for (int rb = 0; rb < 2; rb++) {
    const float linv = 1.0f / lrow[rb];
#pragma unroll
    for (int r = 0; r < 4; r++) {
      int src = (lane & 48) | ((lane >> 2) & 12) | r;
      float lq = __shfl(linv, src, 64);
#pragma unroll
      for (int dt = 0; dt < 4; dt++)
        out[(size_t)(b * T + q0w + rb * 16 + g * 4 + r) * 1024 + h * 64 + dt * 16 + lr] =
            (bf16_t)(acc_o[rb][dt][r] * lq);
    }
  }
}

extern "C" void kernel_launch(void* const* d_in, const int* in_sizes, int n_in,
                              void* d_out, int out_size, void* d_ws, size_t ws_size,
                              hipStream_t stream) {
  (void)in_sizes; (void)n_in; (void)out_size; (void)ws_size;
  const float* x = (const float*)d_in[0];
  const float* w_qkv = (const float*)d_in[1];
  const float* w_out = (const float*)d_in[2];
  float* out = (float*)d_out;
  const int T = 2048, C = 1024;
  const int M = 4 * T;  // 8192

  bf16_t* xb = (bf16_t*)d_ws;                    // [M][C]
  bf16_t* wqkvT = xb + (size_t)M * C;            // [3C][C]
  bf16_t* woutT = wqkvT + (size_t)3 * C * C;     // [C][C]
  bf16_t* qkbuf = woutT + (size_t)C * C;         // [M][2C]
  bf16_t* vT = qkbuf + (size_t)M * 2 * C;        // [B*H][64][T]
  bf16_t* attn = vT + (size_t)M * C;             // [M][C]

  k_cvt_bf16<<<2048, 256, 0, stream>>>(x, xb, M * C / 4);
  k_transpose_cvt<<<dim3(3 * C / 64, C / 64), 256, 0, stream>>>(w_qkv, wqkvT, C, 3 * C);
  k_transpose_cvt<<<dim3(C / 64, C / 64), 256, 0, stream>>>(w_out, woutT, C, C);
  k_gemm<1><<<(3 * C / 128) * (M / 128), 256, 0, stream>>>(xb, wqkvT, qkbuf, vT, M, 3 * C, C,
                                                           3 * C / 128);
  k_attn<<<1024, 256, 0, stream>>>(qkbuf, vT, attn);
  k_gemm<2><<<(C / 128) * (M / 128), 256, 0, stream>>>(attn, woutT, out, nullptr, M, C, C,
                                                       C / 128);
}